// Round 4
// baseline (21.640 us; speedup 1.0000x reference)
//
#include <hip/hip_runtime.h>

// Problem constants (from reference): B=8, N=65536, P=12, G=64
#define BB 8
#define NN 65536
#define PP 12
#define GG 64
#define G3 (GG*GG*GG)        // 262144 = 2^18
#define NBLOCKS 2048         // (B*N)/256

// d_ws layout: [0, 256KB) voxel bitmask (65536 u32 / 32768 u64), then partials.
#define BM_U64_WORDS (BB * G3 / 64)   // 32768
#define PARTIAL_OFF  (BM_U64_WORDS * 8)

// ---------------------------------------------------------------------------
// Pre-pass: pack voxel (B,G,G,G) float {0.0,1.0} into a bitmask, 1 bit/voxel.
// Wave-ballot: 64 lanes read 64 consecutive voxels (coalesced 256B), ballot
// gives the 64-bit mask, lane 0 stores it. 8MB read, 256KB write (~1.3us).
// Bit l of u64 word w == voxel[w*64 + l] != 0; as u32[]: word (idx>>5), bit (idx&31).
__global__ __launch_bounds__(256) void build_mask_kernel(
    const float* __restrict__ voxel, unsigned long long* __restrict__ bm)
{
    int gw   = blockIdx.x * 4 + (threadIdx.x >> 6);   // global wave id, 0..8191
    int lane = threadIdx.x & 63;
    #pragma unroll
    for (int j = 0; j < 4; ++j) {
        int w = gw * 4 + j;                           // u64 word index, 0..32767
        float v = voxel[(size_t)w * 64 + lane];
        unsigned long long m = __ballot(v != 0.0f);
        if (lane == 0) bm[w] = m;
    }
}

// ---------------------------------------------------------------------------
// Contribution of reflecting point (px,py,pz) across raw plane pl.
// Matches reference math: normalize plane in f32, reflect, idx3 = ceil((r+0.5)*G-0.5),
// combine in int32 (wraps identically), clip combined index, mask = 1 - voxel.
__device__ __forceinline__ float plane_contrib(
    float px, float py, float pz, float4 pl,
    const float* __restrict__ cpb, const unsigned int* __restrict__ bmb)
{
    float nx = pl.x, ny = pl.y, nz = pl.z, d = pl.w;
    float norm = sqrtf(nx * nx + ny * ny + nz * nz);
    float inv = 1.0f / norm;
    nx *= inv; ny *= inv; nz *= inv; d *= inv;

    float t = 2.0f * (px * nx + py * ny + pz * nz + d);
    float rx = px - t * nx;
    float ry = py - t * ny;
    float rz = pz - t * nz;

    int ix = (int)ceilf((rx + 0.5f) * 64.0f - 0.5f);
    int iy = (int)ceilf((ry + 0.5f) * 64.0f - 0.5f);
    int iz = (int)ceilf((rz + 0.5f) * 64.0f - 0.5f);
    int idx = ix * 4096 + iy * 64 + iz;
    idx = min(max(idx, 0), G3 - 1);

    // Two independent gathers, issued together:
    //  - bitmask word from a 32KB/batch table (L1-resident per CU)
    //  - cp record: 3 dwords from the 3MB/batch table (L2-resident per XCD)
    unsigned int wbits = bmb[idx >> 5];
    const float* cp = cpb + (size_t)idx * 3;
    float cx = cp[0], cy = cp[1], cz = cp[2];

    float m = ((wbits >> (idx & 31)) & 1u) ? 0.0f : 1.0f;
    float dx = rx - cx;
    float dy = ry - cy;
    float dz = rz - cz;
    return (dx * dx + dy * dy + dz * dz) * m;
}

__global__ __launch_bounds__(256) void sym_plane_main_kernel(
    const float* __restrict__ points,    // (B, N, 3)
    const float* __restrict__ closest,   // (B, G^3, 3)
    const float* __restrict__ planes,    // (B, P, 4)
    const unsigned int* __restrict__ bm, // bitmask, 8192 u32 per batch
    float* __restrict__ partial)         // (NBLOCKS,)
{
    // XCD-aware mapping: blocks round-robin over the 8 XCDs, so batch =
    // blockIdx&7 keeps each batch's gather tables resident in ONE XCD's L2
    // (cp: 3MB) and each CU's L1 (bitmask: 32KB).
    int b = blockIdx.x & 7;
    int i = (blockIdx.x >> 3) * 256 + threadIdx.x;   // 0 .. N-1

    const float* pt = points + ((size_t)b * NN + (size_t)i) * 3;
    // Nontemporal: points are streamed once; don't evict the gather tables.
    float px = __builtin_nontemporal_load(pt + 0);
    float py = __builtin_nontemporal_load(pt + 1);
    float pz = __builtin_nontemporal_load(pt + 2);

    // Flat positions f in [12*i, 12*i+12) all map to point i; plane q = f >> 16.
    int f0 = i * 12;
    int q0 = f0 >> 16;
    int q1 = (f0 + 11) >> 16;

    const float* cpb = closest + (size_t)b * G3 * 3;
    const unsigned int* bmb = bm + b * (G3 / 32);
    const float4* plb = (const float4*)planes + (size_t)b * PP;

    float sum;
    if (q0 == q1) {
        sum = 12.0f * plane_contrib(px, py, pz, plb[q0], cpb, bmb);
    } else {
        int c0 = (q1 << 16) - f0;     // positions using plane q0 (11 threads/batch)
        sum = (float)c0        * plane_contrib(px, py, pz, plb[q0], cpb, bmb)
            + (float)(12 - c0) * plane_contrib(px, py, pz, plb[q1], cpb, bmb);
    }

    // Block reduction: wave64 shuffle, then LDS across 4 waves.
    for (int off = 32; off > 0; off >>= 1)
        sum += __shfl_down(sum, off, 64);

    __shared__ float wsum[4];
    int lane = threadIdx.x & 63;
    int wid  = threadIdx.x >> 6;
    if (lane == 0) wsum[wid] = sum;
    __syncthreads();
    if (threadIdx.x == 0)
        __builtin_nontemporal_store(wsum[0] + wsum[1] + wsum[2] + wsum[3],
                                    partial + blockIdx.x);
}

// Single-block final reduce: overwrites out[0] (no pre-zero needed, fixed
// summation order, no atomics -> deterministic).
__global__ __launch_bounds__(256) void sym_plane_reduce_kernel(
    const float* __restrict__ partial, float* __restrict__ out)
{
    float s = 0.0f;
    for (int j = threadIdx.x; j < NBLOCKS; j += 256)
        s += partial[j];

    for (int off = 32; off > 0; off >>= 1)
        s += __shfl_down(s, off, 64);

    __shared__ float wsum[4];
    int lane = threadIdx.x & 63;
    int wid  = threadIdx.x >> 6;
    if (lane == 0) wsum[wid] = s;
    __syncthreads();
    if (threadIdx.x == 0)
        out[0] = (wsum[0] + wsum[1] + wsum[2] + wsum[3]) * (1.0f / (float)(BB * PP));
}

extern "C" void kernel_launch(void* const* d_in, const int* in_sizes, int n_in,
                              void* d_out, int out_size, void* d_ws, size_t ws_size,
                              hipStream_t stream) {
    const float* voxel   = (const float*)d_in[0];
    const float* points  = (const float*)d_in[1];
    const float* closest = (const float*)d_in[2];
    const float* planes  = (const float*)d_in[3];
    float* out = (float*)d_out;

    unsigned long long* bm64 = (unsigned long long*)d_ws;
    float* partial = (float*)((char*)d_ws + PARTIAL_OFF);

    hipLaunchKernelGGL(build_mask_kernel, dim3(NBLOCKS), dim3(256), 0, stream,
                       voxel, bm64);
    hipLaunchKernelGGL(sym_plane_main_kernel, dim3(NBLOCKS), dim3(256), 0, stream,
                       points, closest, planes, (const unsigned int*)bm64, partial);
    hipLaunchKernelGGL(sym_plane_reduce_kernel, dim3(1), dim3(256), 0, stream,
                       partial, out);
}